// Round 2
// baseline (419.491 us; speedup 1.0000x reference)
//
#include <hip/hip_runtime.h>
#include <stdint.h>

// ModulatedConv2d: B=8, C=512, O=512, K=3, WDIM=512, H=W=64
// Implicit-GEMM formulation: per batch GEMM M=O=512, N=HW=4096, K=9*512=4608,
// with x stored padded-NHWC bf16 so every tap's B-tile is a plain K-contiguous load.

#define MOD_SCALE  0.044194173824159216f   // 1/sqrt(512)
#define CONV_SCALE 0.014731391274719739f   // 1/sqrt(4608)

typedef __attribute__((ext_vector_type(4))) float f32x4;
typedef __attribute__((ext_vector_type(8))) short bf16x8;

__device__ inline unsigned short f2bf(float f) {   // round-to-nearest-even
  uint32_t u = __float_as_uint(f);
  uint32_t r = (u + 0x7fffu + ((u >> 16) & 1u)) >> 16;
  return (unsigned short)r;
}

__device__ inline void gload_lds16(const void* g, void* l) {
  __builtin_amdgcn_global_load_lds(
      (const __attribute__((address_space(1))) void*)g,
      (__attribute__((address_space(3))) void*)l, 16, 0, 0);
}

// ---------- s[b][c] = w[b] . modw[c] * MOD_SCALE + modb[c] + 1 ----------
__global__ __launch_bounds__(256) void k_style(const float* __restrict__ w,
                                               const float* __restrict__ modw,
                                               const float* __restrict__ modb,
                                               float* __restrict__ s_out) {
  int idx = blockIdx.x * 256 + threadIdx.x;      // 0..4095
  int b = idx >> 9, c = idx & 511;
  const float4* wd = (const float4*)(w + (b << 9));
  const float4* md = (const float4*)(modw + (c << 9));
  float acc = 0.f;
#pragma unroll 8
  for (int i = 0; i < 128; ++i) {
    float4 a = wd[i], m = md[i];
    acc += a.x * m.x + a.y * m.y + a.z * m.z + a.w * m.w;
  }
  s_out[idx] = acc * MOD_SCALE + modb[c] + 1.0f;
}

// ---------- wsq[o][c] = sum_k bw[o][c][k]^2 ----------
__global__ __launch_bounds__(256) void k_wsq(const float* __restrict__ bw,
                                             float* __restrict__ wsq) {
  int idx = blockIdx.x * 256 + threadIdx.x;      // o*512+c, 0..262143
  const float* p = bw + (size_t)idx * 9;
  float a = 0.f;
#pragma unroll
  for (int k = 0; k < 9; ++k) a += p[k] * p[k];
  wsq[idx] = a;
}

// ---------- d[b][o] = rsqrt( (1/4608) * sum_c s[b][c]^2 * wsq[o][c] ) ----------
// one wave per (b,o): 4096 waves -> 1024 blocks of 256 threads
__global__ __launch_bounds__(256) void k_demod(const float* __restrict__ s,
                                               const float* __restrict__ wsq,
                                               float* __restrict__ dd) {
  int gw = (blockIdx.x * 256 + threadIdx.x) >> 6;  // wave id = b*512+o
  int lane = threadIdx.x & 63;
  int b = gw >> 9, o = gw & 511;
  const float* sp = s + (b << 9);
  const float* wp = wsq + (o << 9);
  float a = 0.f;
#pragma unroll
  for (int t = 0; t < 8; ++t) {
    int c = lane + (t << 6);
    float sv = sp[c];
    a += sv * sv * wp[c];
  }
#pragma unroll
  for (int off = 32; off > 0; off >>= 1) a += __shfl_down(a, off, 64);
  if (lane == 0) dd[gw] = rsqrtf(a * (1.0f / 4608.0f));
}

// ---------- wmodT[b][o][tap*512+c] = bf16(CONV_SCALE * bw[o][c][tap] * s[b][c] * d[b][o]) ----------
__global__ __launch_bounds__(256) void k_wmod(const float* __restrict__ bw,
                                              const float* __restrict__ s,
                                              const float* __restrict__ dd,
                                              unsigned short* __restrict__ wm) {
  int kk = blockIdx.x * 256 + threadIdx.x;  // 0..4607
  int o = blockIdx.y, b = blockIdx.z;
  int tap = kk >> 9, c = kk & 511;
  float v = bw[(size_t)((o << 9) + c) * 9 + tap] * s[(b << 9) + c] *
            dd[(b << 9) + o] * CONV_SCALE;
  wm[(size_t)((b << 9) + o) * 4608 + kk] = f2bf(v);
}

// ---------- zero xpad (harness poisons ws every call) ----------
__global__ __launch_bounds__(256) void k_zero(uint4* __restrict__ p, int n16) {
  int i = blockIdx.x * 256 + threadIdx.x;
  int stride = gridDim.x * 256;
  uint4 z = make_uint4(0u, 0u, 0u, 0u);
  for (; i < n16; i += stride) p[i] = z;
}

// ---------- xpad[b][py][px][c] = bf16(x[b][c][py-1][px-1]), LDS-tiled transpose ----------
__global__ __launch_bounds__(256) void k_xpose(const float* __restrict__ x,
                                               unsigned short* __restrict__ xp) {
  __shared__ unsigned short tile[64 * 65];
  const int b = blockIdx.z, c0 = blockIdx.y << 6, p0 = blockIdx.x << 6;
  const int tid = threadIdx.x;
  {
    const int pi = tid & 63, ci0 = tid >> 6;
    const float* src = x + (size_t)((b << 9) + c0 + ci0) * 4096 + p0 + pi;
#pragma unroll
    for (int it = 0; it < 16; ++it)
      tile[(ci0 + (it << 2)) * 65 + pi] = f2bf(src[(size_t)(it << 2) * 4096]);
  }
  __syncthreads();
  {
    const int co = tid & 63, po0 = tid >> 6;
#pragma unroll
    for (int it = 0; it < 16; ++it) {
      int p = po0 + (it << 2);
      int gp = p0 + p;
      int py = (gp >> 6) + 1, px = (gp & 63) + 1;
      xp[((size_t)b * 4356 + py * 66 + px) * 512 + c0 + co] = tile[co * 65 + p];
    }
  }
}

// ---------- main conv: m97-structure 128x128 bf16 MFMA GEMM over 9 taps ----------
__global__ __launch_bounds__(256) void k_conv(const unsigned short* __restrict__ wmodT,
                                              const unsigned short* __restrict__ xpad,
                                              float* __restrict__ out) {
  __shared__ alignas(16) unsigned short As[4096];  // 128 rows x 32 k (bf16)
  __shared__ alignas(16) unsigned short Bs[4096];
  const int tid = threadIdx.x;
  const int b  = blockIdx.z;
  const int m0 = blockIdx.y << 7;   // output-channel tile
  const int n0 = blockIdx.x << 7;   // pixel tile (2 image rows)
  const int y0 = n0 >> 6;

  // staging: thread t loads 16B: row = t>>2 (plus +64 on 2nd issue), chunk = (t&3)*8
  const int srow = tid >> 2;
  const int sch  = (tid & 3) << 3;

  const unsigned short* Ab = wmodT + (size_t)((b << 9) + m0 + srow) * 4608 + sch;
  const unsigned short* Xb = xpad + (size_t)b * (66 * 66 * 512) + sch;

  unsigned short* la0 = As + tid * 8;
  unsigned short* la1 = As + 2048 + tid * 8;
  unsigned short* lb0 = Bs + tid * 8;
  unsigned short* lb1 = Bs + 2048 + tid * 8;

  const int lane = tid & 63;
  const int wv   = tid >> 6;
  const int moff = (wv >> 1) << 6;   // wave's 64x64 quadrant
  const int noff = (wv & 1) << 6;
  const int lm   = lane & 15;
  const int lk   = (lane >> 4) << 3;

  const unsigned short* ard0 = As + (moff + lm) * 32 + lk;
  const unsigned short* brd0 = Bs + (noff + lm) * 32 + lk;

  f32x4 acc[4][4];
#pragma unroll
  for (int i = 0; i < 4; ++i)
#pragma unroll
    for (int j = 0; j < 4; ++j) acc[i][j] = (f32x4){0.f, 0.f, 0.f, 0.f};

#pragma unroll 1
  for (int tap = 0; tap < 9; ++tap) {
    const int ky = tap / 3;
    const int kx = tap - ky * 3;
    const unsigned short* Ag = Ab + (tap << 9);
    const unsigned short* Bg = Xb + (size_t)((y0 + ky) * 66 + kx + srow) * 512;
#pragma unroll 1
    for (int cb = 0; cb < 16; ++cb) {
      const unsigned short* a  = Ag + (cb << 5);
      const unsigned short* bb = Bg + (cb << 5);
      gload_lds16(a,              la0);
      gload_lds16(a + 64 * 4608,  la1);
      gload_lds16(bb,             lb0);
      gload_lds16(bb + 66 * 512,  lb1);
      __syncthreads();
      bf16x8 af[4], bf[4];
#pragma unroll
      for (int i = 0; i < 4; ++i) af[i] = *(const bf16x8*)(ard0 + i * 512);
#pragma unroll
      for (int j = 0; j < 4; ++j) bf[j] = *(const bf16x8*)(brd0 + j * 512);
#pragma unroll
      for (int i = 0; i < 4; ++i)
#pragma unroll
        for (int j = 0; j < 4; ++j)
          acc[i][j] = __builtin_amdgcn_mfma_f32_16x16x32_bf16(af[i], bf[j], acc[i][j], 0, 0, 0);
      __syncthreads();
    }
  }

  // epilogue: D lane layout col=lane&15 (pixel), row=(lane>>4)*4+reg (o)
  float* op = out + (size_t)((b << 9) + m0 + moff) * 4096 + n0 + noff;
#pragma unroll
  for (int i = 0; i < 4; ++i) {
#pragma unroll
    for (int r = 0; r < 4; ++r) {
      const int m = i * 16 + ((lane >> 4) << 2) + r;
#pragma unroll
      for (int j = 0; j < 4; ++j)
        op[(size_t)m * 4096 + (j << 4) + lm] = acc[i][j][r];
    }
  }
}

extern "C" void kernel_launch(void* const* d_in, const int* in_sizes, int n_in,
                              void* d_out, int out_size, void* d_ws, size_t ws_size,
                              hipStream_t stream) {
  const float* x    = (const float*)d_in[0];   // (8,512,64,64)
  const float* w    = (const float*)d_in[1];   // (8,512)
  const float* bw   = (const float*)d_in[2];   // (1,512,512,3,3)
  const float* modw = (const float*)d_in[3];   // (512,512)
  const float* modb = (const float*)d_in[4];   // (512,)
  float* out = (float*)d_out;                  // (8,512,64,64) fp32
  char* ws = (char*)d_ws;

  // workspace layout (74,514,432 bytes total):
  float* s_buf  = (float*)(ws);                        // 16 KB
  float* dd_buf = (float*)(ws + 16384);                // 16 KB
  float* wsq    = (float*)(ws + 32768);                // 1 MB
  unsigned short* wmod = (unsigned short*)(ws + 1081344);   // 37,748,736 B
  unsigned short* xpad = (unsigned short*)(ws + 38830080);  // 35,684,352 B

  (void)in_sizes; (void)n_in; (void)out_size; (void)ws_size;

  k_style<<<16, 256, 0, stream>>>(w, modw, modb, s_buf);
  k_wsq  <<<1024, 256, 0, stream>>>(bw, wsq);
  k_demod<<<1024, 256, 0, stream>>>(s_buf, wsq, dd_buf);   // 4096 waves: one per (b,o)
  k_wmod <<<dim3(18, 512, 8), 256, 0, stream>>>(bw, s_buf, dd_buf, wmod);
  k_zero <<<4096, 256, 0, stream>>>((uint4*)xpad, 35684352 / 16);
  k_xpose<<<dim3(64, 8, 8), 256, 0, stream>>>(x, xpad);
  k_conv <<<dim3(32, 4, 8), 256, 0, stream>>>(wmod, xpad, out);
}

// Round 3
// 313.410 us; speedup vs baseline: 1.3385x; 1.3385x over previous
//
#include <hip/hip_runtime.h>
#include <stdint.h>

// ModulatedConv2d: B=8, C=512, O=512, K=3, WDIM=512, H=W=64
// Implicit-GEMM: per batch M=O=512, N=HW=4096, K=9*512=4608.
// x stored padded-NHWC bf16; weights stored K-contiguous per (b,o).
// Conv kernel: 128x128 tile, BK=64 (32KB LDS), global_load_lds width=16,
// XOR-rotation chunk swizzle so ds_read_b128 is 2-way (free) on the banks.

#define MOD_SCALE  0.044194173824159216f   // 1/sqrt(512)
#define CONV_SCALE 0.014731391274719739f   // 1/sqrt(4608)

typedef __attribute__((ext_vector_type(4))) float f32x4;
typedef __attribute__((ext_vector_type(8))) short bf16x8;

__device__ inline unsigned short f2bf(float f) {   // round-to-nearest-even
  uint32_t u = __float_as_uint(f);
  uint32_t r = (u + 0x7fffu + ((u >> 16) & 1u)) >> 16;
  return (unsigned short)r;
}

__device__ inline void gload_lds16(const void* g, void* l) {
  __builtin_amdgcn_global_load_lds(
      (const __attribute__((address_space(1))) void*)g,
      (__attribute__((address_space(3))) void*)l, 16, 0, 0);
}

// ---------- s[b][c] = w[b] . modw[c] * MOD_SCALE + modb[c] + 1 ----------
__global__ __launch_bounds__(256) void k_style(const float* __restrict__ w,
                                               const float* __restrict__ modw,
                                               const float* __restrict__ modb,
                                               float* __restrict__ s_out) {
  int idx = blockIdx.x * 256 + threadIdx.x;      // 0..4095
  int b = idx >> 9, c = idx & 511;
  const float4* wd = (const float4*)(w + (b << 9));
  const float4* md = (const float4*)(modw + (c << 9));
  float acc = 0.f;
#pragma unroll 8
  for (int i = 0; i < 128; ++i) {
    float4 a = wd[i], m = md[i];
    acc += a.x * m.x + a.y * m.y + a.z * m.z + a.w * m.w;
  }
  s_out[idx] = acc * MOD_SCALE + modb[c] + 1.0f;
}

// ---------- wsq[o][c] = sum_k bw[o][c][k]^2 ----------
__global__ __launch_bounds__(256) void k_wsq(const float* __restrict__ bw,
                                             float* __restrict__ wsq) {
  int idx = blockIdx.x * 256 + threadIdx.x;      // o*512+c
  const float* p = bw + (size_t)idx * 9;
  float a = 0.f;
#pragma unroll
  for (int k = 0; k < 9; ++k) a += p[k] * p[k];
  wsq[idx] = a;
}

// ---------- d[b][o] = rsqrt( (1/4608) * sum_c s[b][c]^2 * wsq[o][c] ) ----------
__global__ __launch_bounds__(256) void k_demod(const float* __restrict__ s,
                                               const float* __restrict__ wsq,
                                               float* __restrict__ dd) {
  int gw = (blockIdx.x * 256 + threadIdx.x) >> 6;  // wave id = b*512+o
  int lane = threadIdx.x & 63;
  int b = gw >> 9, o = gw & 511;
  const float* sp = s + (b << 9);
  const float* wp = wsq + (o << 9);
  float a = 0.f;
#pragma unroll
  for (int t = 0; t < 8; ++t) {
    int c = lane + (t << 6);
    float sv = sp[c];
    a += sv * sv * wp[c];
  }
#pragma unroll
  for (int off = 32; off > 0; off >>= 1) a += __shfl_down(a, off, 64);
  if (lane == 0) dd[gw] = rsqrtf(a * (1.0f / 4608.0f));
}

// ---------- wmodT[b][o][tap*512+c] via LDS transpose, coalesced both sides ----------
__global__ __launch_bounds__(256) void k_wmod(const float* __restrict__ bw,
                                              const float* __restrict__ s,
                                              const float* __restrict__ dd,
                                              unsigned short* __restrict__ wm) {
  __shared__ float lw[4608];
  __shared__ float ls[512];
  const int tid = threadIdx.x;
  const int o = blockIdx.x, b = blockIdx.y;
  const float* src = bw + (size_t)o * 4608;
#pragma unroll
  for (int i = 0; i < 18; ++i) lw[tid + (i << 8)] = src[tid + (i << 8)];
  ls[tid] = s[(b << 9) + tid];
  ls[tid + 256] = s[(b << 9) + 256 + tid];
  __syncthreads();
  const float dscale = dd[(b << 9) + o] * CONV_SCALE;
  uint32_t* dst = (uint32_t*)(wm + (size_t)((b << 9) + o) * 4608);
  const int c0 = tid << 1;
  const int base = c0 * 9;
#pragma unroll
  for (int j = 0; j < 9; ++j) {
    float v0 = lw[base + j] * ls[c0] * dscale;
    float v1 = lw[base + 9 + j] * ls[c0 + 1] * dscale;
    dst[(j << 8) + tid] = (uint32_t)f2bf(v0) | ((uint32_t)f2bf(v1) << 16);
  }
}

// ---------- zero ONLY the pad border of xpad (2.1 MB, not 35.7 MB) ----------
__global__ __launch_bounds__(256) void k_border(unsigned short* __restrict__ xp) {
  int p = blockIdx.x, b = blockIdx.y;   // p in [0,260)
  int py, px;
  if (p < 66)       { py = 0;       px = p; }
  else if (p < 132) { py = 65;      px = p - 66; }
  else if (p < 196) { py = p - 131; px = 0; }
  else              { py = p - 195; px = 65; }
  uint32_t* dst = (uint32_t*)(xp + ((size_t)b * 4356 + py * 66 + px) * 512);
  dst[threadIdx.x] = 0u;   // 256 uints = 512 bf16 channels
}

// ---------- xpad[b][py][px][c] = bf16(x[b][c][py-1][px-1]), LDS-tiled transpose ----------
__global__ __launch_bounds__(256) void k_xpose(const float* __restrict__ x,
                                               unsigned short* __restrict__ xp) {
  __shared__ unsigned short tile[64 * 65];
  const int b = blockIdx.z, c0 = blockIdx.y << 6, p0 = blockIdx.x << 6;
  const int tid = threadIdx.x;
  {
    const int pi = tid & 63, ci0 = tid >> 6;
    const float* src = x + (size_t)((b << 9) + c0 + ci0) * 4096 + p0 + pi;
#pragma unroll
    for (int it = 0; it < 16; ++it)
      tile[(ci0 + (it << 2)) * 65 + pi] = f2bf(src[(size_t)(it << 2) * 4096]);
  }
  __syncthreads();
  {
    const int co = tid & 63, po0 = tid >> 6;
#pragma unroll
    for (int it = 0; it < 16; ++it) {
      int p = po0 + (it << 2);
      int gp = p0 + p;
      int py = (gp >> 6) + 1, px = (gp & 63) + 1;
      xp[((size_t)b * 4356 + py * 66 + px) * 512 + c0 + co] = tile[co * 65 + p];
    }
  }
}

// ---------- main conv: 128x128 tile, BK=64, swizzled LDS ----------
// LDS layout (A and B identical): 128 rows x 8 chunks of 16B; logical chunk c of
// row r lives at physical chunk (c+r)&7. 16B-slot p holds row p>>3, so staging
// thread t (gload g) fetches global chunk ((t&7)-((t>>3)&7))&7 of row g*32+(t>>3).
__global__ __launch_bounds__(256, 4) void k_conv(const unsigned short* __restrict__ wmodT,
                                                 const unsigned short* __restrict__ xpad,
                                                 float* __restrict__ out) {
  __shared__ alignas(16) unsigned short As[8192];  // 128 x 64 bf16 = 16KB
  __shared__ alignas(16) unsigned short Bs[8192];
  const int tid = threadIdx.x;
  const int b  = blockIdx.z;
  const int m0 = blockIdx.y << 7;   // output-channel tile
  const int n0 = blockIdx.x << 7;   // pixel tile (2 image rows)
  const int y0 = n0 >> 6;

  const int srow = tid >> 3;                         // 0..31 (row within gload group)
  const int schk = ((tid & 7) - (srow & 7)) & 7;     // logical chunk (swizzle)
  const int scol = schk << 3;                        // shorts

  // A: row m0 + g*32 + srow, k advances +64 shorts per kb step (continuous across taps)
  const unsigned short* Ag = wmodT + (size_t)((b << 9) + m0 + srow) * 4608 + scol;
  const size_t bx = (size_t)b * (66 * 66 * 512);

  const int lane = tid & 63;
  const int wv   = tid >> 6;
  const int moff = (wv >> 1) << 6;
  const int noff = (wv & 1) << 6;
  const int lm   = lane & 15;
  const int g4   = lane >> 4;        // 0..3

  // reader bases: addr = (R0+16i)*64 shorts + ((h*4+g4+R0)&7)*8 shorts
  const unsigned short* ardA[2];
  const unsigned short* ardB[2];
#pragma unroll
  for (int h = 0; h < 2; ++h) {
    ardA[h] = As + (moff + lm) * 64 + ((((h << 2) + g4) + moff + lm) & 7) * 8;
    ardB[h] = Bs + (noff + lm) * 64 + ((((h << 2) + g4) + noff + lm) & 7) * 8;
  }

  f32x4 acc[4][4];
#pragma unroll
  for (int i = 0; i < 4; ++i)
#pragma unroll
    for (int j = 0; j < 4; ++j) acc[i][j] = (f32x4){0.f, 0.f, 0.f, 0.f};

#pragma unroll 1
  for (int tap = 0; tap < 9; ++tap) {
    const int ky = (tap * 11) >> 5;          // tap/3 for tap<9
    const int kx = tap - ky * 3;
    const unsigned short* Bt[4];
#pragma unroll
    for (int g = 0; g < 4; ++g) {
      const int n = (g << 5) + srow;         // 0..127 pixel index within tile
      Bt[g] = xpad + bx +
              (size_t)((y0 + ky + (n >> 6)) * 66 + kx + (n & 63)) * 512 + scol;
    }
#pragma unroll 1
    for (int kb = 0; kb < 8; ++kb) {
#pragma unroll
      for (int g = 0; g < 4; ++g)
        gload_lds16(Ag + g * (32 * 4608), As + (((g << 8) + tid) << 3));
#pragma unroll
      for (int g = 0; g < 4; ++g)
        gload_lds16(Bt[g] + (kb << 6), Bs + (((g << 8) + tid) << 3));
      Ag += 64;
      __syncthreads();
#pragma unroll
      for (int h = 0; h < 2; ++h) {
        bf16x8 af[4], bf[4];
#pragma unroll
        for (int i = 0; i < 4; ++i) af[i] = *(const bf16x8*)(ardA[h] + (i << 10));
#pragma unroll
        for (int j = 0; j < 4; ++j) bf[j] = *(const bf16x8*)(ardB[h] + (j << 10));
#pragma unroll
        for (int i = 0; i < 4; ++i)
#pragma unroll
          for (int j = 0; j < 4; ++j)
            acc[i][j] = __builtin_amdgcn_mfma_f32_16x16x32_bf16(af[i], bf[j], acc[i][j], 0, 0, 0);
      }
      __syncthreads();
    }
  }

  // epilogue: D layout col=lane&15 (pixel), row=(lane>>4)*4+reg (o)
  float* op = out + (size_t)((b << 9) + m0 + moff) * 4096 + n0 + noff;
#pragma unroll
  for (int i = 0; i < 4; ++i) {
#pragma unroll
    for (int r = 0; r < 4; ++r) {
      const int m = i * 16 + (g4 << 2) + r;
#pragma unroll
      for (int j = 0; j < 4; ++j)
        op[(size_t)m * 4096 + (j << 4) + lm] = acc[i][j][r];
    }
  }
}

extern "C" void kernel_launch(void* const* d_in, const int* in_sizes, int n_in,
                              void* d_out, int out_size, void* d_ws, size_t ws_size,
                              hipStream_t stream) {
  const float* x    = (const float*)d_in[0];   // (8,512,64,64)
  const float* w    = (const float*)d_in[1];   // (8,512)
  const float* bw   = (const float*)d_in[2];   // (1,512,512,3,3)
  const float* modw = (const float*)d_in[3];   // (512,512)
  const float* modb = (const float*)d_in[4];   // (512,)
  float* out = (float*)d_out;                  // (8,512,64,64) fp32
  char* ws = (char*)d_ws;

  float* s_buf  = (float*)(ws);                        // 16 KB
  float* dd_buf = (float*)(ws + 16384);                // 16 KB
  float* wsq    = (float*)(ws + 32768);                // 1 MB
  unsigned short* wmod = (unsigned short*)(ws + 1081344);   // 37,748,736 B
  unsigned short* xpad = (unsigned short*)(ws + 38830080);  // 35,684,352 B

  (void)in_sizes; (void)n_in; (void)out_size; (void)ws_size;

  k_style <<<16, 256, 0, stream>>>(w, modw, modb, s_buf);
  k_wsq   <<<1024, 256, 0, stream>>>(bw, wsq);
  k_demod <<<1024, 256, 0, stream>>>(s_buf, wsq, dd_buf);
  k_wmod  <<<dim3(512, 8), 256, 0, stream>>>(bw, s_buf, dd_buf, wmod);
  k_border<<<dim3(260, 8), 256, 0, stream>>>(xpad);
  k_xpose <<<dim3(64, 8, 8), 256, 0, stream>>>(x, xpad);
  k_conv  <<<dim3(32, 4, 8), 256, 0, stream>>>(wmod, xpad, out);
}

// Round 4
// 301.226 us; speedup vs baseline: 1.3926x; 1.0404x over previous
//
#include <hip/hip_runtime.h>
#include <stdint.h>

// ModulatedConv2d: B=8, C=512, O=512, K=3, WDIM=512, H=W=64
// Implicit-GEMM: per batch M=O=512, N=HW=4096, K=9*512=4608.
// x stored padded-NHWC bf16; weights stored K-contiguous per (b,o).
// Conv kernel: 128x128 tile, BK=64 (32KB LDS), global_load_lds width=16,
// XOR-rotation chunk swizzle -> 0 LDS bank conflicts (verified round 3).
// Prep fused into 2 kernels (k_style + k_fw) to cut launch+traffic overhead.

#define MOD_SCALE  0.044194173824159216f   // 1/sqrt(512)
#define CONV_SCALE 0.014731391274719739f   // 1/sqrt(4608)

typedef __attribute__((ext_vector_type(4))) float f32x4;
typedef __attribute__((ext_vector_type(8))) short bf16x8;

__device__ inline unsigned short f2bf(float f) {   // round-to-nearest-even
  uint32_t u = __float_as_uint(f);
  uint32_t r = (u + 0x7fffu + ((u >> 16) & 1u)) >> 16;
  return (unsigned short)r;
}

__device__ inline void gload_lds16(const void* g, void* l) {
  __builtin_amdgcn_global_load_lds(
      (const __attribute__((address_space(1))) void*)g,
      (__attribute__((address_space(3))) void*)l, 16, 0, 0);
}

// ---------- s[b][c] = w[b] . modw[c] * MOD_SCALE + modb[c] + 1 ----------
// 4-way split-K per dot: block=(cblk,b), thread t: c=cblk*64+(t>>2), quarter=t&3
__global__ __launch_bounds__(256) void k_style(const float* __restrict__ w,
                                               const float* __restrict__ modw,
                                               const float* __restrict__ modb,
                                               float* __restrict__ s_out) {
  __shared__ float red[256];
  const int t = threadIdx.x;
  const int cb = blockIdx.x, b = blockIdx.y;
  const int cl = t >> 2, q = t & 3;
  const int c = (cb << 6) + cl;
  const float4* wd = (const float4*)(w + (b << 9) + (q << 7));
  const float4* md = (const float4*)(modw + ((size_t)c << 9) + (q << 7));
  float acc = 0.f;
#pragma unroll
  for (int i = 0; i < 32; ++i) {
    float4 a = wd[i], m = md[i];
    acc += a.x * m.x + a.y * m.y + a.z * m.z + a.w * m.w;
  }
  red[t] = acc;
  __syncthreads();
  if (t < 64) {
    float v = red[t * 4] + red[t * 4 + 1] + red[t * 4 + 2] + red[t * 4 + 3];
    int cc = (cb << 6) + t;
    s_out[(b << 9) + cc] = v * MOD_SCALE + modb[cc] + 1.0f;
  }
}

// ---------- fused wsq + demod + wmod: one block per o ----------
// wmodT[b][o][tap*512+c] = bf16(CONV_SCALE * bw[o][c][tap] * s[b][c] * d[b][o])
__global__ __launch_bounds__(256) void k_fw(const float* __restrict__ bw,
                                            const float* __restrict__ s,
                                            unsigned short* __restrict__ wm) {
  __shared__ float lw[4608];   // bw row, [c][tap]
  __shared__ float ls[4096];   // s, [b][c]
  __shared__ float red[32];    // [b][wave]
  __shared__ float sc8[8];
  const int tid = threadIdx.x;
  const int o = blockIdx.x;
  {
    const float4* src = (const float4*)(bw + (size_t)o * 4608);
    float4* dst = (float4*)lw;
#pragma unroll
    for (int i = 0; i < 4; ++i) dst[tid + (i << 8)] = src[tid + (i << 8)];
    if (tid < 128) dst[tid + 1024] = src[tid + 1024];   // 1152 float4 total
  }
  {
    const float4* src = (const float4*)s;
    float4* dst = (float4*)ls;
#pragma unroll
    for (int i = 0; i < 4; ++i) dst[tid + (i << 8)] = src[tid + (i << 8)];
  }
  __syncthreads();
  const int c0 = tid << 1;
  const int base = c0 * 9;
  float wq0 = 0.f, wq1 = 0.f;
#pragma unroll
  for (int j = 0; j < 9; ++j) {
    float a = lw[base + j];     wq0 += a * a;
    float b2 = lw[base + 9 + j]; wq1 += b2 * b2;
  }
  const int lane = tid & 63, wv = tid >> 6;
#pragma unroll
  for (int b = 0; b < 8; ++b) {
    float s0 = ls[(b << 9) + c0], s1 = ls[(b << 9) + c0 + 1];
    float v = wq0 * s0 * s0 + wq1 * s1 * s1;
#pragma unroll
    for (int off = 32; off > 0; off >>= 1) v += __shfl_down(v, off, 64);
    if (lane == 0) red[(b << 2) + wv] = v;
  }
  __syncthreads();
  if (tid < 8) {
    float a = red[tid << 2] + red[(tid << 2) + 1] + red[(tid << 2) + 2] + red[(tid << 2) + 3];
    sc8[tid] = rsqrtf(a * (1.0f / 4608.0f)) * CONV_SCALE;
  }
  __syncthreads();
#pragma unroll 1
  for (int b = 0; b < 8; ++b) {
    const float dsc = sc8[b];
    const float s0 = ls[(b << 9) + c0] * dsc;
    const float s1 = ls[(b << 9) + c0 + 1] * dsc;
    uint32_t* dst = (uint32_t*)(wm + (size_t)((b << 9) + o) * 4608);
#pragma unroll
    for (int j = 0; j < 9; ++j) {
      float v0 = lw[base + j] * s0;
      float v1 = lw[base + 9 + j] * s1;
      dst[(j << 8) + tid] = (uint32_t)f2bf(v0) | ((uint32_t)f2bf(v1) << 16);
    }
  }
}

// ---------- zero ONLY the pad border of xpad (2.1 MB, not 35.7 MB) ----------
__global__ __launch_bounds__(256) void k_border(unsigned short* __restrict__ xp) {
  int p = blockIdx.x, b = blockIdx.y;   // p in [0,260)
  int py, px;
  if (p < 66)       { py = 0;       px = p; }
  else if (p < 132) { py = 65;      px = p - 66; }
  else if (p < 196) { py = p - 131; px = 0; }
  else              { py = p - 195; px = 65; }
  uint32_t* dst = (uint32_t*)(xp + ((size_t)b * 4356 + py * 66 + px) * 512);
  dst[threadIdx.x] = 0u;   // 256 uints = 512 bf16 channels
}

// ---------- xpad[b][py][px][c] = bf16(x[b][c][py-1][px-1]), LDS-tiled transpose ----------
__global__ __launch_bounds__(256) void k_xpose(const float* __restrict__ x,
                                               unsigned short* __restrict__ xp) {
  __shared__ unsigned short tile[64 * 65];
  const int b = blockIdx.z, c0 = blockIdx.y << 6, p0 = blockIdx.x << 6;
  const int tid = threadIdx.x;
  {
    const int pi = tid & 63, ci0 = tid >> 6;
    const float* src = x + (size_t)((b << 9) + c0 + ci0) * 4096 + p0 + pi;
#pragma unroll
    for (int it = 0; it < 16; ++it)
      tile[(ci0 + (it << 2)) * 65 + pi] = f2bf(src[(size_t)(it << 2) * 4096]);
  }
  __syncthreads();
  {
    const int co = tid & 63, po0 = tid >> 6;
#pragma unroll
    for (int it = 0; it < 16; ++it) {
      int p = po0 + (it << 2);
      int gp = p0 + p;
      int py = (gp >> 6) + 1, px = (gp & 63) + 1;
      xp[((size_t)b * 4356 + py * 66 + px) * 512 + c0 + co] = tile[co * 65 + p];
    }
  }
}

// ---------- main conv: 128x128 tile, BK=64, swizzled LDS (unchanged, verified) ----------
// LDS layout (A and B identical): 128 rows x 8 chunks of 16B; logical chunk c of
// row r lives at physical chunk (c+r)&7. 16B-slot p holds row p>>3, so staging
// thread t (gload g) fetches global chunk ((t&7)-((t>>3)&7))&7 of row g*32+(t>>3).
__global__ __launch_bounds__(256, 4) void k_conv(const unsigned short* __restrict__ wmodT,
                                                 const unsigned short* __restrict__ xpad,
                                                 float* __restrict__ out) {
  __shared__ alignas(16) unsigned short As[8192];  // 128 x 64 bf16 = 16KB
  __shared__ alignas(16) unsigned short Bs[8192];
  const int tid = threadIdx.x;
  const int b  = blockIdx.z;
  const int m0 = blockIdx.y << 7;   // output-channel tile
  const int n0 = blockIdx.x << 7;   // pixel tile (2 image rows)
  const int y0 = n0 >> 6;

  const int srow = tid >> 3;                         // 0..31
  const int schk = ((tid & 7) - (srow & 7)) & 7;     // logical chunk (swizzle)
  const int scol = schk << 3;                        // shorts

  const unsigned short* Ag = wmodT + (size_t)((b << 9) + m0 + srow) * 4608 + scol;
  const size_t bx = (size_t)b * (66 * 66 * 512);

  const int lane = tid & 63;
  const int wv   = tid >> 6;
  const int moff = (wv >> 1) << 6;
  const int noff = (wv & 1) << 6;
  const int lm   = lane & 15;
  const int g4   = lane >> 4;        // 0..3

  const unsigned short* ardA[2];
  const unsigned short* ardB[2];
#pragma unroll
  for (int h = 0; h < 2; ++h) {
    ardA[h] = As + (moff + lm) * 64 + ((((h << 2) + g4) + moff + lm) & 7) * 8;
    ardB[h] = Bs + (noff + lm) * 64 + ((((h << 2) + g4) + noff + lm) & 7) * 8;
  }

  f32x4 acc[4][4];
#pragma unroll
  for (int i = 0; i < 4; ++i)
#pragma unroll
    for (int j = 0; j < 4; ++j) acc[i][j] = (f32x4){0.f, 0.f, 0.f, 0.f};

#pragma unroll 1
  for (int tap = 0; tap < 9; ++tap) {
    const int ky = (tap * 11) >> 5;          // tap/3 for tap<9
    const int kx = tap - ky * 3;
    const unsigned short* Bt[4];
#pragma unroll
    for (int g = 0; g < 4; ++g) {
      const int n = (g << 5) + srow;         // 0..127 pixel index within tile
      Bt[g] = xpad + bx +
              (size_t)((y0 + ky + (n >> 6)) * 66 + kx + (n & 63)) * 512 + scol;
    }
#pragma unroll 1
    for (int kb = 0; kb < 8; ++kb) {
#pragma unroll
      for (int g = 0; g < 4; ++g)
        gload_lds16(Ag + g * (32 * 4608), As + (((g << 8) + tid) << 3));
#pragma unroll
      for (int g = 0; g < 4; ++g)
        gload_lds16(Bt[g] + (kb << 6), Bs + (((g << 8) + tid) << 3));
      Ag += 64;
      __syncthreads();
#pragma unroll
      for (int h = 0; h < 2; ++h) {
        bf16x8 af[4], bf[4];
#pragma unroll
        for (int i = 0; i < 4; ++i) af[i] = *(const bf16x8*)(ardA[h] + (i << 10));
#pragma unroll
        for (int j = 0; j < 4; ++j) bf[j] = *(const bf16x8*)(ardB[h] + (j << 10));
#pragma unroll
        for (int i = 0; i < 4; ++i)
#pragma unroll
          for (int j = 0; j < 4; ++j)
            acc[i][j] = __builtin_amdgcn_mfma_f32_16x16x32_bf16(af[i], bf[j], acc[i][j], 0, 0, 0);
      }
      __syncthreads();
    }
  }

  float* op = out + (size_t)((b << 9) + m0 + moff) * 4096 + n0 + noff;
#pragma unroll
  for (int i = 0; i < 4; ++i) {
#pragma unroll
    for (int r = 0; r < 4; ++r) {
      const int m = i * 16 + (g4 << 2) + r;
#pragma unroll
      for (int j = 0; j < 4; ++j)
        op[(size_t)m * 4096 + (j << 4) + lm] = acc[i][j][r];
    }
  }
}

extern "C" void kernel_launch(void* const* d_in, const int* in_sizes, int n_in,
                              void* d_out, int out_size, void* d_ws, size_t ws_size,
                              hipStream_t stream) {
  const float* x    = (const float*)d_in[0];   // (8,512,64,64)
  const float* w    = (const float*)d_in[1];   // (8,512)
  const float* bw   = (const float*)d_in[2];   // (1,512,512,3,3)
  const float* modw = (const float*)d_in[3];   // (512,512)
  const float* modb = (const float*)d_in[4];   // (512,)
  float* out = (float*)d_out;                  // (8,512,64,64) fp32
  char* ws = (char*)d_ws;

  float* s_buf = (float*)(ws);                              // 16 KB
  unsigned short* wmod = (unsigned short*)(ws + 16384);     // 37,748,736 B
  unsigned short* xpad = (unsigned short*)(ws + 37765120);  // 35,684,352 B

  (void)in_sizes; (void)n_in; (void)out_size; (void)ws_size;

  k_style <<<dim3(8, 8), 256, 0, stream>>>(w, modw, modb, s_buf);
  k_fw    <<<512, 256, 0, stream>>>(bw, s_buf, wmod);
  k_border<<<dim3(260, 8), 256, 0, stream>>>(xpad);
  k_xpose <<<dim3(64, 8, 8), 256, 0, stream>>>(x, xpad);
  k_conv  <<<dim3(32, 4, 8), 256, 0, stream>>>(wmod, xpad, out);
}

// Round 5
// 265.620 us; speedup vs baseline: 1.5793x; 1.1341x over previous
//
#include <hip/hip_runtime.h>
#include <stdint.h>

// ModulatedConv2d: B=8, C=512, O=512, K=3, WDIM=512, H=W=64
// Implicit-GEMM: per batch M=O=512, N=HW=4096, K=9*512=4608.
// Round-5 k_conv: per (ky,kb) stage one 132-pixel B halo strip (shared by the
// 3 kx taps) + 3 A tap-panels, one barrier pair per 96 MFMA/wave.
// Barriers 144->48, staging -33%, LDS 66KB (2 blocks/CU).

#define MOD_SCALE  0.044194173824159216f   // 1/sqrt(512)
#define CONV_SCALE 0.014731391274719739f   // 1/sqrt(4608)

typedef __attribute__((ext_vector_type(4))) float f32x4;
typedef __attribute__((ext_vector_type(8))) short bf16x8;

__device__ inline unsigned short f2bf(float f) {   // round-to-nearest-even
  uint32_t u = __float_as_uint(f);
  uint32_t r = (u + 0x7fffu + ((u >> 16) & 1u)) >> 16;
  return (unsigned short)r;
}

__device__ inline void gload_lds16(const void* g, void* l) {
  __builtin_amdgcn_global_load_lds(
      (const __attribute__((address_space(1))) void*)g,
      (__attribute__((address_space(3))) void*)l, 16, 0, 0);
}

// ---------- fused prep: xpose (blk<4096) + border zero (<6176) + style ----------
__global__ __launch_bounds__(256) void k_prep(const float* __restrict__ x,
                                              const float* __restrict__ w,
                                              const float* __restrict__ modw,
                                              const float* __restrict__ modb,
                                              unsigned short* __restrict__ xp,
                                              float* __restrict__ s_out) {
  __shared__ unsigned short smem[64 * 65];
  const int blk = blockIdx.x;
  const int tid = threadIdx.x;
  if (blk < 4096) {
    // ---- xpad[b][py][px][c] = bf16(x[b][c][py-1][px-1]) ----
    const int b = blk >> 9, r = blk & 511;
    const int c0 = ((r >> 6) << 6), p0 = ((r & 63) << 6);
    {
      const int pi = tid & 63, ci0 = tid >> 6;
      const float* src = x + (size_t)((b << 9) + c0 + ci0) * 4096 + p0 + pi;
#pragma unroll
      for (int it = 0; it < 16; ++it)
        smem[(ci0 + (it << 2)) * 65 + pi] = f2bf(src[(size_t)(it << 2) * 4096]);
    }
    __syncthreads();
    {
      const int cq = tid & 31, pq = tid >> 5;   // c-pair, pixel-in-group
#pragma unroll
      for (int it = 0; it < 8; ++it) {
        const int p = pq + (it << 3);
        const int gp = p0 + p;
        const int py = (gp >> 6) + 1, px = (gp & 63) + 1;
        uint32_t v = (uint32_t)smem[(cq << 1) * 65 + p] |
                     ((uint32_t)smem[((cq << 1) + 1) * 65 + p] << 16);
        ((uint32_t*)(xp + ((size_t)b * 4356 + py * 66 + px) * 512 + c0))[cq] = v;
      }
    }
  } else if (blk < 6176) {
    // ---- zero pad border (260 segments x 8 batches) ----
    const int q = blk - 4096;
    const int b = q / 260, p = q - b * 260;
    int py, px;
    if (p < 66)       { py = 0;       px = p; }
    else if (p < 132) { py = 65;      px = p - 66; }
    else if (p < 196) { py = p - 131; px = 0; }
    else              { py = p - 195; px = 65; }
    uint32_t* dst = (uint32_t*)(xp + ((size_t)b * 4356 + py * 66 + px) * 512);
    dst[tid] = 0u;
  } else {
    // ---- s[b][c] = w[b].modw[c]*MOD_SCALE + modb[c] + 1, 4-way split-K ----
    float* red = (float*)smem;
    const int sb = blk - 6176;
    const int cb = sb & 7, b = sb >> 3;
    const int cl = tid >> 2, qq = tid & 3;
    const int c = (cb << 6) + cl;
    const float4* wd = (const float4*)(w + (b << 9) + (qq << 7));
    const float4* md = (const float4*)(modw + ((size_t)c << 9) + (qq << 7));
    float acc = 0.f;
#pragma unroll
    for (int i = 0; i < 32; ++i) {
      float4 a = wd[i], m = md[i];
      acc += a.x * m.x + a.y * m.y + a.z * m.z + a.w * m.w;
    }
    red[tid] = acc;
    __syncthreads();
    if (tid < 64) {
      float v = red[tid * 4] + red[tid * 4 + 1] + red[tid * 4 + 2] + red[tid * 4 + 3];
      int cc = (cb << 6) + tid;
      s_out[(b << 9) + cc] = v * MOD_SCALE + modb[cc] + 1.0f;
    }
  }
}

// ---------- fused wsq + demod + wmod: one block per o (verified round 4) ----------
__global__ __launch_bounds__(256) void k_fw(const float* __restrict__ bw,
                                            const float* __restrict__ s,
                                            unsigned short* __restrict__ wm) {
  __shared__ float lw[4608];   // bw row, [c][tap]
  __shared__ float ls[4096];   // s, [b][c]
  __shared__ float red[32];
  __shared__ float sc8[8];
  const int tid = threadIdx.x;
  const int o = blockIdx.x;
  {
    const float4* src = (const float4*)(bw + (size_t)o * 4608);
    float4* dst = (float4*)lw;
#pragma unroll
    for (int i = 0; i < 4; ++i) dst[tid + (i << 8)] = src[tid + (i << 8)];
    if (tid < 128) dst[tid + 1024] = src[tid + 1024];
  }
  {
    const float4* src = (const float4*)s;
    float4* dst = (float4*)ls;
#pragma unroll
    for (int i = 0; i < 4; ++i) dst[tid + (i << 8)] = src[tid + (i << 8)];
  }
  __syncthreads();
  const int c0 = tid << 1;
  const int base = c0 * 9;
  float wq0 = 0.f, wq1 = 0.f;
#pragma unroll
  for (int j = 0; j < 9; ++j) {
    float a = lw[base + j];      wq0 += a * a;
    float b2 = lw[base + 9 + j]; wq1 += b2 * b2;
  }
  const int lane = tid & 63, wv = tid >> 6;
#pragma unroll
  for (int b = 0; b < 8; ++b) {
    float s0 = ls[(b << 9) + c0], s1 = ls[(b << 9) + c0 + 1];
    float v = wq0 * s0 * s0 + wq1 * s1 * s1;
#pragma unroll
    for (int off = 32; off > 0; off >>= 1) v += __shfl_down(v, off, 64);
    if (lane == 0) red[(b << 2) + wv] = v;
  }
  __syncthreads();
  if (tid < 8) {
    float a = red[tid << 2] + red[(tid << 2) + 1] + red[(tid << 2) + 2] + red[(tid << 2) + 3];
    sc8[tid] = rsqrtf(a * (1.0f / 4608.0f)) * CONV_SCALE;
  }
  __syncthreads();
#pragma unroll 1
  for (int b = 0; b < 8; ++b) {
    const float dsc = sc8[b];
    const float s0 = ls[(b << 9) + c0] * dsc;
    const float s1 = ls[(b << 9) + c0 + 1] * dsc;
    uint32_t* dst = (uint32_t*)(wm + (size_t)((b << 9) + o) * 4608);
#pragma unroll
    for (int j = 0; j < 9; ++j) {
      float v0 = lw[base + j] * s0;
      float v1 = lw[base + 9 + j] * s1;
      dst[(j << 8) + tid] = (uint32_t)f2bf(v0) | ((uint32_t)f2bf(v1) << 16);
    }
  }
}

// ---------- main conv: 128x128 tile, BK=64, B-halo shared across kx taps ----------
// LDS: As = 3 tap-panels of 128 rows x 64 k; Bs = 132-pixel halo strip x 64 k.
// XOR-rotation chunk swizzle (round-3, 0 conflicts): logical chunk c of row r
// at physical chunk (c+r)&7; staging thread t fetches chunk ((t&7)-((t>>3)&7))&7.
__global__ __launch_bounds__(256, 2) void k_conv(const unsigned short* __restrict__ wmodT,
                                                 const unsigned short* __restrict__ xpad,
                                                 float* __restrict__ out) {
  __shared__ alignas(16) unsigned short As[3 * 8192];  // 48 KB
  __shared__ alignas(16) unsigned short Bs[8448];      // 16.5 KB
  const int tid = threadIdx.x;
  const int b  = blockIdx.z;
  const int m0 = blockIdx.y << 7;
  const int n0 = blockIdx.x << 7;
  const int y0 = n0 >> 6;

  const int srow = tid >> 3;                         // 0..31
  const int schk = ((tid & 7) - (srow & 7)) & 7;     // swizzled logical chunk
  const int scol = schk << 3;

  const unsigned short* A0 = wmodT + (size_t)((b << 9) + m0 + srow) * 4608 + scol;
  const size_t bx = (size_t)b * (66 * 66 * 512);

  const int lane = tid & 63;
  const int wv   = tid >> 6;
  const int moff = (wv >> 1) << 6;
  const int noff = (wv & 1) << 6;
  const int noffp = noff ? 66 : 0;   // halo-strip row base for this wave
  const int lm   = lane & 15;
  const int g4   = lane >> 4;

  // A reader bases (chunk const across i since 16i = 0 mod 8); +kx*8192 selects panel
  const unsigned short* ardA[2];
#pragma unroll
  for (int h = 0; h < 2; ++h)
    ardA[h] = As + (moff + lm) * 64 + ((((h << 2) + g4) + moff + lm) & 7) * 8;
  // B reader bases per (kx,h): row = noffp + lm + kx (+16j)
  const unsigned short* ardB[3][2];
#pragma unroll
  for (int kx = 0; kx < 3; ++kx) {
    const int rb = noffp + lm + kx;
#pragma unroll
    for (int h = 0; h < 2; ++h)
      ardB[kx][h] = Bs + rb * 64 + ((((h << 2) + g4) + rb) & 7) * 8;
  }

  f32x4 acc[4][4];
#pragma unroll
  for (int i = 0; i < 4; ++i)
#pragma unroll
    for (int j = 0; j < 4; ++j) acc[i][j] = (f32x4){0.f, 0.f, 0.f, 0.f};

#pragma unroll 1
  for (int ky = 0; ky < 3; ++ky) {
    const unsigned short* Bp0 = xpad + bx + (size_t)((y0 + ky) * 66 + srow) * 512 + scol;
#pragma unroll 1
    for (int kb = 0; kb < 8; ++kb) {
      const int kcol = kb << 6;
      // stage 3 A tap-panels
#pragma unroll
      for (int kx = 0; kx < 3; ++kx) {
        const unsigned short* Ap = A0 + ((ky * 3 + kx) << 9) + kcol;
#pragma unroll
        for (int g = 0; g < 4; ++g)
          gload_lds16(Ap + g * (32 * 4608), As + ((kx << 13) + (((g << 8) + tid) << 3)));
      }
      // stage B halo strip: 132 rows (linear: pixel offset = (y0+ky)*66 + hr)
      const unsigned short* Bp = Bp0 + kcol;
#pragma unroll
      for (int g = 0; g < 4; ++g)
        gload_lds16(Bp + g * (32 * 512), Bs + (((g << 8) + tid) << 3));
      if (tid < 32) gload_lds16(Bp + 128 * 512, Bs + 8192 + tid * 8);
      __syncthreads();
#pragma unroll
      for (int kx = 0; kx < 3; ++kx) {
#pragma unroll
        for (int h = 0; h < 2; ++h) {
          bf16x8 af[4], bf[4];
          const unsigned short* pa = ardA[h] + (kx << 13);
          const unsigned short* pb = ardB[kx][h];
#pragma unroll
          for (int i = 0; i < 4; ++i) af[i] = *(const bf16x8*)(pa + (i << 10));
#pragma unroll
          for (int j = 0; j < 4; ++j) bf[j] = *(const bf16x8*)(pb + (j << 10));
#pragma unroll
          for (int i = 0; i < 4; ++i)
#pragma unroll
            for (int j = 0; j < 4; ++j)
              acc[i][j] = __builtin_amdgcn_mfma_f32_16x16x32_bf16(af[i], bf[j], acc[i][j], 0, 0, 0);
        }
      }
      __syncthreads();
    }
  }

  // epilogue: D layout col=lane&15 (pixel), row=(lane>>4)*4+reg (o)
  float* op = out + (size_t)((b << 9) + m0 + moff) * 4096 + n0 + noff;
#pragma unroll
  for (int i = 0; i < 4; ++i) {
#pragma unroll
    for (int r = 0; r < 4; ++r) {
      const int m = i * 16 + (g4 << 2) + r;
#pragma unroll
      for (int j = 0; j < 4; ++j)
        op[(size_t)m * 4096 + (j << 4) + lm] = acc[i][j][r];
    }
  }
}

extern "C" void kernel_launch(void* const* d_in, const int* in_sizes, int n_in,
                              void* d_out, int out_size, void* d_ws, size_t ws_size,
                              hipStream_t stream) {
  const float* x    = (const float*)d_in[0];   // (8,512,64,64)
  const float* w    = (const float*)d_in[1];   // (8,512)
  const float* bw   = (const float*)d_in[2];   // (1,512,512,3,3)
  const float* modw = (const float*)d_in[3];   // (512,512)
  const float* modb = (const float*)d_in[4];   // (512,)
  float* out = (float*)d_out;                  // (8,512,64,64) fp32
  char* ws = (char*)d_ws;

  float* s_buf = (float*)(ws);                              // 16 KB
  unsigned short* wmod = (unsigned short*)(ws + 16384);     // 37,748,736 B
  unsigned short* xpad = (unsigned short*)(ws + 37765120);  // 35,684,352 B

  (void)in_sizes; (void)n_in; (void)out_size; (void)ws_size;

  k_prep<<<6240, 256, 0, stream>>>(x, w, modw, modb, xpad, s_buf);
  k_fw  <<<512, 256, 0, stream>>>(bw, s_buf, wmod);
  k_conv<<<dim3(32, 4, 8), 256, 0, stream>>>(wmod, xpad, out);
}